// Round 1
// baseline (356.257 us; speedup 1.0000x reference)
//
#include <hip/hip_runtime.h>
#include <math.h>

#define KBINS 8
#define R_MIN -5.0f
#define R_MAX 5.0f
#define MIN_BIN 1e-4f
#define MIN_SLOPE 1e-4f

// d_ws float layout:
// [0..8]    x_pos (9)
// [9..17]   y_pos (9)
// [18..26]  slopes (9)
// [28..91]  per-bin packed (16-float-aligned at 28): bin b -> 8 floats:
//           {x_k, 1/width, y_k, height, s, slope_k, slope_k1, 0}
// [92]      log(slopes[0])
// [93]      log(slopes[K])

__global__ void rqs_params_kernel(const float* __restrict__ p, float* __restrict__ ws) {
    if (threadIdx.x != 0 || blockIdx.x != 0) return;
    float w[KBINS], h[KBINS], sl[KBINS + 1];
    const float scale = (R_MAX - R_MIN) - KBINS * MIN_BIN;

    // softmax widths
    float m = -1e30f;
    for (int i = 0; i < KBINS; ++i) m = fmaxf(m, p[i]);
    float sum = 0.f;
    for (int i = 0; i < KBINS; ++i) { w[i] = expf(p[i] - m); sum += w[i]; }
    for (int i = 0; i < KBINS; ++i) w[i] = w[i] / sum * scale + MIN_BIN;

    // softmax heights
    m = -1e30f;
    for (int i = 0; i < KBINS; ++i) m = fmaxf(m, p[KBINS + i]);
    sum = 0.f;
    for (int i = 0; i < KBINS; ++i) { h[i] = expf(p[KBINS + i] - m); sum += h[i]; }
    for (int i = 0; i < KBINS; ++i) h[i] = h[i] / sum * scale + MIN_BIN;

    // softplus slopes
    const float off = logf(expf(1.0f - MIN_SLOPE) - 1.0f);
    for (int i = 0; i <= KBINS; ++i) {
        float z = p[2 * KBINS + i] + off;
        float sp = (z > 20.f) ? z : log1pf(expf(z));
        sl[i] = sp + MIN_SLOPE;
    }

    float xp[KBINS + 1], yp[KBINS + 1];
    xp[0] = R_MIN; yp[0] = R_MIN;
    for (int i = 0; i < KBINS; ++i) { xp[i + 1] = xp[i] + w[i]; yp[i + 1] = yp[i] + h[i]; }

    for (int i = 0; i <= KBINS; ++i) {
        ws[i] = xp[i];
        ws[9 + i] = yp[i];
        ws[18 + i] = sl[i];
    }
    for (int b = 0; b < KBINS; ++b) {
        float width  = xp[b + 1] - xp[b];
        float height = yp[b + 1] - yp[b];
        float* q = ws + 28 + b * 8;
        q[0] = xp[b];
        q[1] = 1.0f / width;
        q[2] = yp[b];
        q[3] = height;
        q[4] = height / width;
        q[5] = sl[b];
        q[6] = sl[b + 1];
        q[7] = 0.f;
    }
    ws[92] = logf(sl[0]);
    ws[93] = logf(sl[KBINS]);
}

__global__ __launch_bounds__(256) void rqs_main_kernel(
        const float4* __restrict__ x4,
        const float*  __restrict__ ws,
        float4* __restrict__ y4,
        float4* __restrict__ ld4,
        int n4) {
    __shared__ float4 sbin[2 * KBINS];   // bin b: sbin[2b] = {xk,invw,yk,h}, sbin[2b+1] = {s,sk,sk1,_}

    const int tid = threadIdx.x;
    if (tid < 2 * KBINS) sbin[tid] = ((const float4*)(ws + 28))[tid];
    __syncthreads();

    const int i = blockIdx.x * blockDim.x + tid;
    if (i >= n4) return;

    // wave-uniform values -> compiler scalarizes to s_load
    const float e1 = ws[1], e2 = ws[2], e3 = ws[3], e4 = ws[4],
                e5 = ws[5], e6 = ws[6], e7 = ws[7];
    const float sl0 = ws[18], slK = ws[26];
    const float lsl0 = ws[92], lslK = ws[93];

    const float4 xv = x4[i];
    const float xs[4] = {xv.x, xv.y, xv.z, xv.w};
    float ys[4], lds_[4];

    #pragma unroll
    for (int j = 0; j < 4; ++j) {
        const float x = xs[j];
        // searchsorted(x_pos[1:-1], x, 'right') == count(edge <= x)
        int b = (int)(x >= e1) + (int)(x >= e2) + (int)(x >= e3) + (int)(x >= e4)
              + (int)(x >= e5) + (int)(x >= e6) + (int)(x >= e7);

        const float4 q0 = sbin[2 * b];
        const float4 q1 = sbin[2 * b + 1];

        float xi = (x - q0.x) * q0.y;
        xi = fminf(fmaxf(xi, 0.f), 1.f);
        const float s = q1.x, sk = q1.y, sk1 = q1.z;
        const float xi1m = 1.f - xi;
        const float xx = xi * xi1m;
        const float num  = s * xi * xi + sk * xx;
        const float den  = s + (sk1 + sk - 2.f * s) * xx;
        const float invd = 1.f / den;
        float y = q0.z + q0.w * num * invd;
        const float dnum  = s * s * (sk1 * xi * xi + 2.f * s * xx + sk * xi1m * xi1m);
        const float deriv = dnum * invd * invd;
        float ld = __logf(deriv);

        const bool below = x < R_MIN;
        const bool above = x > R_MAX;
        const float yl = (x - R_MIN) * sl0 + R_MIN;
        const float yr = (x - R_MAX) * slK + R_MAX;
        y  = above ? yr  : y;
        y  = below ? yl  : y;
        ld = above ? lslK : ld;
        ld = below ? lsl0 : ld;

        ys[j] = y;
        lds_[j] = ld;
    }

    y4[i]  = make_float4(ys[0], ys[1], ys[2], ys[3]);
    ld4[i] = make_float4(lds_[0], lds_[1], lds_[2], lds_[3]);
}

extern "C" void kernel_launch(void* const* d_in, const int* in_sizes, int n_in,
                              void* d_out, int out_size, void* d_ws, size_t ws_size,
                              hipStream_t stream) {
    const float* x = (const float*)d_in[0];
    const float* p = (const float*)d_in[1];
    float* out = (float*)d_out;
    float* ws  = (float*)d_ws;
    const int N = in_sizes[0];
    const int n4 = N / 4;   // N = 33554432, divisible by 4

    rqs_params_kernel<<<1, 64, 0, stream>>>(p, ws);
    rqs_main_kernel<<<(n4 + 255) / 256, 256, 0, stream>>>(
        (const float4*)x, ws, (float4*)out, (float4*)out + n4, n4);
}